// Round 1
// baseline (19863.515 us; speedup 1.0000x reference)
//
#include <hip/hip_runtime.h>

#define D 128
#define N_ITEMS 200000
#define N_USERS 100000
#define TI 32   // items per score-kernel tile

#define INV_SQRT_D 0.088388347648318447f

// ---------------------------------------------------------------------------
// Scatter spmm: out[dst[e]] += val[e] * x[src[e]]   (out must be pre-zeroed)
// 32 threads per edge, float4 per thread (128 dims).
// ---------------------------------------------------------------------------
__global__ __launch_bounds__(256) void spmm_atomic_kernel(
    const int* __restrict__ src, const int* __restrict__ dst,
    const float* __restrict__ val, const float* __restrict__ x,
    float* __restrict__ out, int E)
{
    int t = blockIdx.x * 256 + threadIdx.x;
    int e = t >> 5;
    if (e >= E) return;
    int lane = t & 31;
    int s = src[e], d = dst[e];
    float v = val[e];
    float4 xv = ((const float4*)x)[(size_t)s * 32 + lane];
    float* o = out + (size_t)d * D + (lane << 2);
    atomicAdd(o + 0, v * xv.x);
    atomicAdd(o + 1, v * xv.y);
    atomicAdd(o + 2, v * xv.z);
    atomicAdd(o + 3, v * xv.w);
}

// ---------------------------------------------------------------------------
// Gated-attention score kernel.
// One block = 32 items. For each relation r: stage I_r (64KB) in LDS, build
// T^T[k][item] = x*nb in LDS (stride 36 words: 16B-aligned, conflict-free),
// compute Y = T @ I with 4x4 register micro-tiles, leaky-relu, row-sum via
// shfl, then softmax over the 3 relation scores -> w[item][3].
// ---------------------------------------------------------------------------
__global__ __launch_bounds__(256) void score_kernel(
    const float* __restrict__ x,
    const float* __restrict__ nb0, const float* __restrict__ nb1,
    const float* __restrict__ nb2,
    const float* __restrict__ I0, const float* __restrict__ I1,
    const float* __restrict__ I2,
    float* __restrict__ w_out)   // [N_ITEMS*3]
{
    __shared__ float Ild[D * D];       // 64 KB
    __shared__ float Tt[D * 36];       // 18 KB, padded stride 36
    const int tid = threadIdx.x;
    const int jg = tid & 31;           // j-group: j0 = jg*4
    const int ig = tid >> 5;           // i-group: i0 = ig*4
    const int j0 = jg << 2, i0 = ig << 2;
    const int itemBase = blockIdx.x * TI;

    const float* nbs[3] = {nb0, nb1, nb2};
    const float* Is[3]  = {I0, I1, I2};
    float sreg[3][4];

    for (int rel = 0; rel < 3; ++rel) {
        __syncthreads();  // previous iteration done reading Ild/Tt
        // stage I_rel
        {
            const float4* Ig = (const float4*)Is[rel];
            float4* Il4 = (float4*)Ild;
            #pragma unroll
            for (int t = 0; t < 16; ++t) Il4[tid + t * 256] = Ig[tid + t * 256];
        }
        // build T^T
        for (int t = tid; t < TI * D; t += 256) {
            int il = t >> 7;        // local item
            int dd = t & 127;       // dim
            size_t gi = (size_t)(itemBase + il) * D + dd;
            Tt[dd * 36 + il] = x[gi] * nbs[rel][gi];
        }
        __syncthreads();

        float acc[4][4];
        #pragma unroll
        for (int a = 0; a < 4; ++a)
            #pragma unroll
            for (int b = 0; b < 4; ++b) acc[a][b] = 0.f;

        #pragma unroll 4
        for (int k = 0; k < D; ++k) {
            float4 iv = *(const float4*)&Ild[k * D + j0];
            float4 tv = *(const float4*)&Tt[k * 36 + i0];
            acc[0][0] += tv.x * iv.x; acc[0][1] += tv.x * iv.y;
            acc[0][2] += tv.x * iv.z; acc[0][3] += tv.x * iv.w;
            acc[1][0] += tv.y * iv.x; acc[1][1] += tv.y * iv.y;
            acc[1][2] += tv.y * iv.z; acc[1][3] += tv.y * iv.w;
            acc[2][0] += tv.z * iv.x; acc[2][1] += tv.z * iv.y;
            acc[2][2] += tv.z * iv.z; acc[2][3] += tv.z * iv.w;
            acc[3][0] += tv.w * iv.x; acc[3][1] += tv.w * iv.y;
            acc[3][2] += tv.w * iv.z; acc[3][3] += tv.w * iv.w;
        }

        float ps[4];
        #pragma unroll
        for (int a = 0; a < 4; ++a) {
            float s = 0.f;
            #pragma unroll
            for (int b = 0; b < 4; ++b) {
                float h = acc[a][b];
                s += (h >= 0.f) ? h : 0.2f * h;
            }
            ps[a] = s;
        }
        // reduce across the 32 j-groups (contiguous lanes within half-wave)
        #pragma unroll
        for (int off = 16; off; off >>= 1) {
            #pragma unroll
            for (int a = 0; a < 4; ++a)
                ps[a] += __shfl_down(ps[a], off, 32);
        }
        if (jg == 0) {
            #pragma unroll
            for (int a = 0; a < 4; ++a) sreg[rel][a] = ps[a] * INV_SQRT_D;
        }
    }

    if (jg == 0) {
        #pragma unroll
        for (int a = 0; a < 4; ++a) {
            float s0 = sreg[0][a], s1 = sreg[1][a], s2 = sreg[2][a];
            float m = fmaxf(s0, fmaxf(s1, s2));
            float e0 = expf(s0 - m), e1 = expf(s1 - m), e2 = expf(s2 - m);
            float inv = 1.f / (e0 + e1 + e2);
            int item = itemBase + i0 + a;
            w_out[item * 3 + 0] = e0 * inv;
            w_out[item * 3 + 1] = e1 * inv;
            w_out[item * 3 + 2] = e2 * inv;
        }
    }
}

// ---------------------------------------------------------------------------
// neighbor = w0*nb0 + w1*nb1 + w2*nb2.  nb0 aliases out (in-place safe: each
// thread reads its own element before writing it).
// ---------------------------------------------------------------------------
__global__ __launch_bounds__(256) void combine_kernel(
    const float4* __restrict__ nb0, const float4* __restrict__ nb1,
    const float4* __restrict__ nb2, const float* __restrict__ w,
    float4* __restrict__ out)
{
    int idx = blockIdx.x * 256 + threadIdx.x;
    if (idx >= N_ITEMS * 32) return;
    int item = idx >> 5;
    float w0 = w[item * 3 + 0], w1 = w[item * 3 + 1], w2 = w[item * 3 + 2];
    float4 a = nb0[idx], b = nb1[idx], c = nb2[idx];
    float4 r;
    r.x = a.x * w0 + b.x * w1 + c.x * w2;
    r.y = a.y * w0 + b.y * w1 + c.y * w2;
    r.z = a.z * w0 + b.z * w1 + c.z * w2;
    r.w = a.w * w0 + b.w * w1 + c.w * w2;
    out[idx] = r;
}

extern "C" void kernel_launch(void* const* d_in, const int* in_sizes, int n_in,
                              void* d_out, int out_size, void* d_ws, size_t ws_size,
                              hipStream_t stream) {
    const float* x       = (const float*)d_in[1];
    const int*   src0    = (const int*)d_in[2];
    const int*   dst0    = (const int*)d_in[3];
    const float* val0    = (const float*)d_in[4];
    const int*   src1    = (const int*)d_in[5];
    const int*   dst1    = (const int*)d_in[6];
    const float* val1    = (const float*)d_in[7];
    const int*   src2    = (const int*)d_in[8];
    const int*   dst2    = (const int*)d_in[9];
    const float* val2    = (const float*)d_in[10];
    const int*   src_ui  = (const int*)d_in[11];
    const int*   dst_ui  = (const int*)d_in[12];
    const float* val_ui  = (const float*)d_in[13];
    const float* I0      = (const float*)d_in[14];
    const float* I1      = (const float*)d_in[15];
    const float* I2      = (const float*)d_in[16];

    const int E_ii = in_sizes[2];
    const int E_ui = in_sizes[11];

    float* u_emb = (float*)d_out;                          // [N_USERS*D]
    float* nb0   = (float*)d_out + (size_t)N_USERS * D;    // neighbor slot doubles as nb_in
    float* nb1   = (float*)d_ws;                           // [N_ITEMS*D]
    float* nb2   = (float*)d_ws + (size_t)N_ITEMS * D;
    float* w     = (float*)d_ws + (size_t)2 * N_ITEMS * D; // [N_ITEMS*3]

    // zero accumulators (d_out/d_ws are poisoned 0xAA before each launch)
    hipMemsetAsync(d_out, 0, (size_t)(N_USERS + N_ITEMS) * D * sizeof(float), stream);
    hipMemsetAsync(d_ws, 0, (size_t)2 * N_ITEMS * D * sizeof(float), stream);

    // scatter spmms
    {
        int grid = (E_ii * 32 + 255) / 256;
        spmm_atomic_kernel<<<grid, 256, 0, stream>>>(src0, dst0, val0, x, nb0, E_ii);
        spmm_atomic_kernel<<<grid, 256, 0, stream>>>(src1, dst1, val1, x, nb1, E_ii);
        spmm_atomic_kernel<<<grid, 256, 0, stream>>>(src2, dst2, val2, x, nb2, E_ii);
        int grid_ui = (E_ui * 32 + 255) / 256;
        spmm_atomic_kernel<<<grid_ui, 256, 0, stream>>>(src_ui, dst_ui, val_ui, x, u_emb, E_ui);
    }

    // gated-attention scores -> softmax weights
    score_kernel<<<N_ITEMS / TI, 256, 0, stream>>>(x, nb0, nb1, nb2, I0, I1, I2, w);

    // weighted combine (in-place over nb0 == neighbor output region)
    combine_kernel<<<(N_ITEMS * 32 + 255) / 256, 256, 0, stream>>>(
        (const float4*)nb0, (const float4*)nb1, (const float4*)nb2, w, (float4*)nb0);
}

// Round 2
// 3134.143 us; speedup vs baseline: 6.3378x; 6.3378x over previous
//
#include <hip/hip_runtime.h>

#define D 128
#define N_ITEMS 200000
#define N_USERS 100000
#define TI 32   // items per score-kernel tile

#define INV_SQRT_D 0.088388347648318447f

// ---------------------------------------------------------------------------
// CSR build: histogram -> 3-kernel exclusive scan -> scatter pairs
// ---------------------------------------------------------------------------
__global__ __launch_bounds__(256) void hist_kernel(
    const int* __restrict__ dst, unsigned* __restrict__ counts, int E)
{
    int e = blockIdx.x * 256 + threadIdx.x;
    if (e < E) atomicAdd(&counts[dst[e]], 1u);
}

__global__ __launch_bounds__(256) void scan1_kernel(
    const unsigned* __restrict__ counts, unsigned* __restrict__ offsets,
    unsigned* __restrict__ blocksums, int n)
{
    __shared__ unsigned s[256];
    int tid = threadIdx.x;
    int i = blockIdx.x * 256 + tid;
    unsigned v = (i < n) ? counts[i] : 0u;
    s[tid] = v; __syncthreads();
    #pragma unroll
    for (int off = 1; off < 256; off <<= 1) {
        unsigned t = (tid >= off) ? s[tid - off] : 0u;
        __syncthreads();
        s[tid] += t;
        __syncthreads();
    }
    if (i < n) offsets[i] = s[tid] - v;          // exclusive within block
    if (tid == 255) blocksums[blockIdx.x] = s[255];
}

__global__ __launch_bounds__(1024) void scan2_kernel(
    unsigned* __restrict__ blocksums, int nb)
{
    __shared__ unsigned s[1024];
    int tid = threadIdx.x;
    unsigned v = (tid < nb) ? blocksums[tid] : 0u;
    s[tid] = v; __syncthreads();
    #pragma unroll
    for (int off = 1; off < 1024; off <<= 1) {
        unsigned t = (tid >= off) ? s[tid - off] : 0u;
        __syncthreads();
        s[tid] += t;
        __syncthreads();
    }
    if (tid < nb) blocksums[tid] = s[tid] - v;   // exclusive
}

__global__ __launch_bounds__(256) void scan3_kernel(
    unsigned* __restrict__ offsets, unsigned* __restrict__ cursor,
    const unsigned* __restrict__ blocksums, int n, unsigned Etot)
{
    int i = blockIdx.x * 256 + threadIdx.x;
    if (i < n) {
        unsigned o = offsets[i] + blocksums[blockIdx.x];
        offsets[i] = o;
        cursor[i] = o;
    }
    if (i == 0) offsets[n] = Etot;
}

__global__ __launch_bounds__(256) void scatter_kernel(
    const int* __restrict__ src, const int* __restrict__ dst,
    const float* __restrict__ val, unsigned* __restrict__ cursor,
    int2* __restrict__ pairs, int E)
{
    int e = blockIdx.x * 256 + threadIdx.x;
    if (e >= E) return;
    unsigned pos = atomicAdd(&cursor[dst[e]], 1u);
    pairs[pos] = make_int2(src[e], __float_as_int(val[e]));
}

// ---------------------------------------------------------------------------
// Gather spmm: one 32-lane group per dst row; register accumulation; one
// coalesced non-atomic float4 store per lane. No pre-zeroing needed.
// ---------------------------------------------------------------------------
__global__ __launch_bounds__(256) void gather_spmm_kernel(
    const unsigned* __restrict__ offsets, const int2* __restrict__ pairs,
    const float4* __restrict__ x4, float4* __restrict__ out4, int nrows)
{
    int row = blockIdx.x * 8 + (threadIdx.x >> 5);
    if (row >= nrows) return;
    int lane = threadIdx.x & 31;
    unsigned j = offsets[row], end = offsets[row + 1];
    float4 acc = make_float4(0.f, 0.f, 0.f, 0.f);
    for (; j + 2 <= end; j += 2) {
        int2 p0 = pairs[j];
        int2 p1 = pairs[j + 1];
        float4 a = x4[(size_t)p0.x * 32 + lane];
        float4 b = x4[(size_t)p1.x * 32 + lane];
        float v0 = __int_as_float(p0.y), v1 = __int_as_float(p1.y);
        acc.x = fmaf(v0, a.x, acc.x); acc.y = fmaf(v0, a.y, acc.y);
        acc.z = fmaf(v0, a.z, acc.z); acc.w = fmaf(v0, a.w, acc.w);
        acc.x = fmaf(v1, b.x, acc.x); acc.y = fmaf(v1, b.y, acc.y);
        acc.z = fmaf(v1, b.z, acc.z); acc.w = fmaf(v1, b.w, acc.w);
    }
    if (j < end) {
        int2 p0 = pairs[j];
        float4 a = x4[(size_t)p0.x * 32 + lane];
        float v0 = __int_as_float(p0.y);
        acc.x = fmaf(v0, a.x, acc.x); acc.y = fmaf(v0, a.y, acc.y);
        acc.z = fmaf(v0, a.z, acc.z); acc.w = fmaf(v0, a.w, acc.w);
    }
    out4[(size_t)row * 32 + lane] = acc;
}

// ---------------------------------------------------------------------------
// Gated-attention score kernel (unchanged from round 1).
// ---------------------------------------------------------------------------
__global__ __launch_bounds__(256) void score_kernel(
    const float* __restrict__ x,
    const float* __restrict__ nb0, const float* __restrict__ nb1,
    const float* __restrict__ nb2,
    const float* __restrict__ I0, const float* __restrict__ I1,
    const float* __restrict__ I2,
    float* __restrict__ w_out)   // [N_ITEMS*3]
{
    __shared__ float Ild[D * D];       // 64 KB
    __shared__ float Tt[D * 36];       // 18 KB, padded stride 36
    const int tid = threadIdx.x;
    const int jg = tid & 31;
    const int ig = tid >> 5;
    const int j0 = jg << 2, i0 = ig << 2;
    const int itemBase = blockIdx.x * TI;

    const float* nbs[3] = {nb0, nb1, nb2};
    const float* Is[3]  = {I0, I1, I2};
    float sreg[3][4];

    for (int rel = 0; rel < 3; ++rel) {
        __syncthreads();
        {
            const float4* Ig = (const float4*)Is[rel];
            float4* Il4 = (float4*)Ild;
            #pragma unroll
            for (int t = 0; t < 16; ++t) Il4[tid + t * 256] = Ig[tid + t * 256];
        }
        for (int t = tid; t < TI * D; t += 256) {
            int il = t >> 7;
            int dd = t & 127;
            size_t gi = (size_t)(itemBase + il) * D + dd;
            Tt[dd * 36 + il] = x[gi] * nbs[rel][gi];
        }
        __syncthreads();

        float acc[4][4];
        #pragma unroll
        for (int a = 0; a < 4; ++a)
            #pragma unroll
            for (int b = 0; b < 4; ++b) acc[a][b] = 0.f;

        #pragma unroll 4
        for (int k = 0; k < D; ++k) {
            float4 iv = *(const float4*)&Ild[k * D + j0];
            float4 tv = *(const float4*)&Tt[k * 36 + i0];
            acc[0][0] += tv.x * iv.x; acc[0][1] += tv.x * iv.y;
            acc[0][2] += tv.x * iv.z; acc[0][3] += tv.x * iv.w;
            acc[1][0] += tv.y * iv.x; acc[1][1] += tv.y * iv.y;
            acc[1][2] += tv.y * iv.z; acc[1][3] += tv.y * iv.w;
            acc[2][0] += tv.z * iv.x; acc[2][1] += tv.z * iv.y;
            acc[2][2] += tv.z * iv.z; acc[2][3] += tv.z * iv.w;
            acc[3][0] += tv.w * iv.x; acc[3][1] += tv.w * iv.y;
            acc[3][2] += tv.w * iv.z; acc[3][3] += tv.w * iv.w;
        }

        float ps[4];
        #pragma unroll
        for (int a = 0; a < 4; ++a) {
            float s = 0.f;
            #pragma unroll
            for (int b = 0; b < 4; ++b) {
                float h = acc[a][b];
                s += (h >= 0.f) ? h : 0.2f * h;
            }
            ps[a] = s;
        }
        #pragma unroll
        for (int off = 16; off; off >>= 1) {
            #pragma unroll
            for (int a = 0; a < 4; ++a)
                ps[a] += __shfl_down(ps[a], off, 32);
        }
        if (jg == 0) {
            #pragma unroll
            for (int a = 0; a < 4; ++a) sreg[rel][a] = ps[a] * INV_SQRT_D;
        }
    }

    if (jg == 0) {
        #pragma unroll
        for (int a = 0; a < 4; ++a) {
            float s0 = sreg[0][a], s1 = sreg[1][a], s2 = sreg[2][a];
            float m = fmaxf(s0, fmaxf(s1, s2));
            float e0 = expf(s0 - m), e1 = expf(s1 - m), e2 = expf(s2 - m);
            float inv = 1.f / (e0 + e1 + e2);
            int item = itemBase + i0 + a;
            w_out[item * 3 + 0] = e0 * inv;
            w_out[item * 3 + 1] = e1 * inv;
            w_out[item * 3 + 2] = e2 * inv;
        }
    }
}

__global__ __launch_bounds__(256) void combine_kernel(
    const float4* __restrict__ nb0, const float4* __restrict__ nb1,
    const float4* __restrict__ nb2, const float* __restrict__ w,
    float4* __restrict__ out)
{
    int idx = blockIdx.x * 256 + threadIdx.x;
    if (idx >= N_ITEMS * 32) return;
    int item = idx >> 5;
    float w0 = w[item * 3 + 0], w1 = w[item * 3 + 1], w2 = w[item * 3 + 2];
    float4 a = nb0[idx], b = nb1[idx], c = nb2[idx];
    float4 r;
    r.x = a.x * w0 + b.x * w1 + c.x * w2;
    r.y = a.y * w0 + b.y * w1 + c.y * w2;
    r.z = a.z * w0 + b.z * w1 + c.z * w2;
    r.w = a.w * w0 + b.w * w1 + c.w * w2;
    out[idx] = r;
}

extern "C" void kernel_launch(void* const* d_in, const int* in_sizes, int n_in,
                              void* d_out, int out_size, void* d_ws, size_t ws_size,
                              hipStream_t stream) {
    const float* x       = (const float*)d_in[1];
    const int*   src0    = (const int*)d_in[2];
    const int*   dst0    = (const int*)d_in[3];
    const float* val0    = (const float*)d_in[4];
    const int*   src1    = (const int*)d_in[5];
    const int*   dst1    = (const int*)d_in[6];
    const float* val1    = (const float*)d_in[7];
    const int*   src2    = (const int*)d_in[8];
    const int*   dst2    = (const int*)d_in[9];
    const float* val2    = (const float*)d_in[10];
    const int*   src_ui  = (const int*)d_in[11];
    const int*   dst_ui  = (const int*)d_in[12];
    const float* val_ui  = (const float*)d_in[13];
    const float* I0      = (const float*)d_in[14];
    const float* I1      = (const float*)d_in[15];
    const float* I2      = (const float*)d_in[16];

    const int E_ii = in_sizes[2];
    const int E_ui = in_sizes[11];

    float* u_emb = (float*)d_out;                          // [N_USERS*D], written last
    float* nb0   = (float*)d_out + (size_t)N_USERS * D;    // neighbor slot doubles as nb_in

    // workspace layout
    float*    nb1       = (float*)d_ws;                                  // 25.6M floats
    float*    nb2       = nb1 + (size_t)N_ITEMS * D;                     // 25.6M floats
    float*    w         = nb2 + (size_t)N_ITEMS * D;                     // 600k floats
    unsigned* cc        = (unsigned*)(w + (size_t)N_ITEMS * 3);          // counts/cursor [N_ITEMS]
    unsigned* offsets   = cc + N_ITEMS;                                  // [N_ITEMS+1]
    unsigned* blocksums = offsets + N_ITEMS + 1;                         // [1024]
    uintptr_t pu        = ((uintptr_t)(blocksums + 1024) + 15) & ~(uintptr_t)15;
    int2*     pairs_ui  = (int2*)pu;                                     // [E_ui]
    // ii pairs live in the u_emb output region (free until the final ui gather)
    int2*     pairs_ii  = (int2*)d_out;                                  // 25.6 MB <= 51.2 MB region

    auto build_and_gather = [&](const int* src, const int* dst, const float* val,
                                int E, int nrows, int2* pairs, float* out) {
        hipMemsetAsync(cc, 0, (size_t)nrows * sizeof(unsigned), stream);
        int gE = (E + 255) / 256;
        int gN = (nrows + 255) / 256;
        hist_kernel<<<gE, 256, 0, stream>>>(dst, cc, E);
        scan1_kernel<<<gN, 256, 0, stream>>>(cc, offsets, blocksums, nrows);
        scan2_kernel<<<1, 1024, 0, stream>>>(blocksums, gN);
        scan3_kernel<<<gN, 256, 0, stream>>>(offsets, cc, blocksums, nrows, (unsigned)E);
        scatter_kernel<<<gE, 256, 0, stream>>>(src, dst, val, cc, pairs, E);
        gather_spmm_kernel<<<(nrows + 7) / 8, 256, 0, stream>>>(
            offsets, pairs, (const float4*)x, (float4*)out, nrows);
    };

    // item-item relations (pairs scratch in u_emb region)
    build_and_gather(src0, dst0, val0, E_ii, N_ITEMS, pairs_ii, nb0);
    build_and_gather(src1, dst1, val1, E_ii, N_ITEMS, pairs_ii, nb1);
    build_and_gather(src2, dst2, val2, E_ii, N_ITEMS, pairs_ii, nb2);

    // gated-attention scores -> softmax weights
    score_kernel<<<N_ITEMS / TI, 256, 0, stream>>>(x, nb0, nb1, nb2, I0, I1, I2, w);

    // weighted combine (in-place over nb0 == neighbor output region)
    combine_kernel<<<(N_ITEMS * 32 + 255) / 256, 256, 0, stream>>>(
        (const float4*)nb0, (const float4*)nb1, (const float4*)nb2, w, (float4*)nb0);

    // user-item last (writes u_emb region, whose pairs scratch is now dead)
    build_and_gather(src_ui, dst_ui, val_ui, E_ui, N_USERS, pairs_ui, u_emb);
}